// Round 3
// baseline (686.018 us; speedup 1.0000x reference)
//
#include <hip/hip_runtime.h>
#include <hip/hip_bf16.h>

#define TPB 256

// One thread per input row. All decisions (signs, argmax scores, branch errors)
// computed in FP64 to match the harness's float64 numpy reference
// decision-for-decision. Key fact: for rows where both +/-0.25 branches pick
// the same final point v, pe == me BIT-EXACTLY in fp64 (fl64(x+-0.25) is exact,
// so d_p = fl64(x - v) = d_m), giving the deterministic which=False the fp64
// reference produces. fp32 cannot reproduce this (fl32(x+0.25) rounds).
// Output d_out is float32: [final_vals (N*8) | final_idxs (N)].
__global__ __launch_bounds__(TPB) void e8p_kernel(
    const float* __restrict__ X,
    const float* __restrict__ grid_part,
    const float* __restrict__ grid_part_norm,
    const int*   __restrict__ allcombo_idx,
    const int*   __restrict__ idx_map,
    float* __restrict__ out,
    int N, int G)
{
    // LDS layout (8B-aligned first): norms as double, codewords as float, idx_map.
    extern __shared__ double ldsd[];
    double* cn = ldsd;                       // G doubles
    float*  cw = (float*)(ldsd + G);         // 8*G floats
    int*    im = (int*)(cw + 8 * G);         // 256 ints

    const int tid = threadIdx.x;
    for (int k = tid; k < G; k += TPB)     cn[k] = (double)grid_part_norm[k];
    for (int k = tid; k < 8 * G; k += TPB) cw[k] = grid_part[k];
    if (tid < 256) im[tid] = idx_map[tid];
    __syncthreads();

    const int i = blockIdx.x * TPB + tid;
    if (i >= N) return;

    const float4* X4 = (const float4*)(X + (size_t)i * 8);
    float4 a = X4[0], b = X4[1];
    float x[8] = {a.x, a.y, a.z, a.w, b.x, b.y, b.z, b.w};

    // Branch prep in fp64: Y = x +/- 0.25 (exact), signs, |Y| with coord0
    // negated on odd #neg; mint = bitmask (coord j -> bit 7-j).
    double yap[8], yam[8];
    int negp = 0, negm = 0;
#pragma unroll
    for (int j = 0; j < 8; ++j) {
        const double xd = (double)x[j];
        const double ypj = xd + 0.25;
        const double ymj = xd - 0.25;
        if (ypj < 0.0) negp |= (1 << (7 - j));
        if (ymj < 0.0) negm |= (1 << (7 - j));
        yap[j] = fabs(ypj);
        yam[j] = fabs(ymj);
    }
    int mintp = negp, mintm = negm;
    if (__popc(negp) & 1) { yap[0] = -yap[0]; mintp ^= 128; }
    if (__popc(negm) & 1) { yam[0] = -yam[0]; mintm ^= 128; }

    // Argmax over codebook in fp64: score = 2*(Ya . g) - ||g||^2.
    // Products (fp32 value * exact half-integer) are exact in double, so the
    // fp64 argmax equals the true real-arithmetic argmax (ties measure-zero).
    // First-max-wins matches np.argmax.
    double bestp = -1e300, bestm = -1e300;
    int qp = 0, qm = 0;
    for (int j = 0; j < G; ++j) {
        const float4 g0 = *(const float4*)(cw + (size_t)j * 8);
        const float4 g1 = *(const float4*)(cw + (size_t)j * 8 + 4);
        const double n = cn[j];
        const double t0 = (double)g0.x, t1 = (double)g0.y,
                     t2 = (double)g0.z, t3 = (double)g0.w,
                     t4 = (double)g1.x, t5 = (double)g1.y,
                     t6 = (double)g1.z, t7 = (double)g1.w;
        double dp, dm;
        dp = yap[0] * t0;           dm = yam[0] * t0;
        dp = fma(yap[1], t1, dp);   dm = fma(yam[1], t1, dm);
        dp = fma(yap[2], t2, dp);   dm = fma(yam[2], t2, dm);
        dp = fma(yap[3], t3, dp);   dm = fma(yam[3], t3, dm);
        dp = fma(yap[4], t4, dp);   dm = fma(yam[4], t4, dm);
        dp = fma(yap[5], t5, dp);   dm = fma(yam[5], t5, dm);
        dp = fma(yap[6], t6, dp);   dm = fma(yam[6], t6, dm);
        dp = fma(yap[7], t7, dp);   dm = fma(yam[7], t7, dm);
        const double sp = 2.0 * dp - n;
        const double sm = 2.0 * dm - n;
        if (sp > bestp) { bestp = sp; qp = j; }
        if (sm > bestm) { bestm = sm; qm = j; }
    }

    // Epilogue in fp64: vals = grid[q]*mask; err = sqrt(sum((Y - vals)^2)).
    const float* gp_ = cw + (size_t)qp * 8;
    const float* gm_ = cw + (size_t)qm * 8;
    double vp[8], vm[8];
    double ep2 = 0.0, em2 = 0.0;
#pragma unroll
    for (int j = 0; j < 8; ++j) {
        const double maskp = ((mintp >> (7 - j)) & 1) ? -1.0 : 1.0;
        const double maskm = ((mintm >> (7 - j)) & 1) ? -1.0 : 1.0;
        vp[j] = (double)gp_[j] * maskp;      // exact
        vm[j] = (double)gm_[j] * maskm;      // exact
        const double xd = (double)x[j];
        const double dpj = (xd + 0.25) - vp[j];  // = fl64(x - (vp-0.25))
        const double dmj = (xd - 0.25) - vm[j];  // = fl64(x - (vm+0.25))
        ep2 += dpj * dpj;
        em2 += dmj * dmj;
    }
    const double ep = sqrt(ep2), em = sqrt(em2);
    const bool which = ep < em;   // strict <; exact ties -> false (minus branch)

    const int rowp = im[mintp];
    const int rowm = im[mintm];
    const int pi = allcombo_idx[(size_t)rowp * G + qp];
    const int mi = allcombo_idx[(size_t)rowm * G + qm];
    // grid_idx_map[k] == int16(k - 2^15): which ? pi : mi - 32768
    const float idxval = which ? (float)pi : (float)(mi - 32768);

    float* vout = out + (size_t)i * 8;
#pragma unroll
    for (int j = 0; j < 8; ++j) {
        const double v = which ? (vp[j] - 0.25) : (vm[j] + 0.25);
        vout[j] = (float)v;   // multiples of 0.25: exact
    }
    out[(size_t)N * 8 + i] = idxval;
}

extern "C" void kernel_launch(void* const* d_in, const int* in_sizes, int n_in,
                              void* d_out, int out_size, void* d_ws, size_t ws_size,
                              hipStream_t stream) {
    const float* X    = (const float*)d_in[0];
    const float* gp   = (const float*)d_in[1];
    const float* gn   = (const float*)d_in[2];
    const int*   aci  = (const int*)d_in[3];
    const int*   imap = (const int*)d_in[4];
    // d_in[5] (int_map) and d_in[6] (grid_idx_map) are folded analytically.

    const int N = in_sizes[0] / 8;
    const int G = in_sizes[1] / 8;
    // LDS: G doubles (norms) + 8G floats (codewords) + 256 ints (idx_map)
    const size_t shmem = (size_t)G * 8 + (size_t)8 * G * 4 + 256 * 4;
    const int blocks = (N + TPB - 1) / TPB;

    hipLaunchKernelGGL(e8p_kernel, dim3(blocks), dim3(TPB), shmem, stream,
                       X, gp, gn, aci, imap, (float*)d_out, N, G);
}

// Round 4
// 237.554 us; speedup vs baseline: 2.8878x; 2.8878x over previous
//
#include <hip/hip_runtime.h>
#include <hip/hip_bf16.h>

#define TPB 256
// Margins (halved-score domain / squared-err domain). fp32 error bound is
// ~2e-5 at these magnitudes (|score| <= ~30); 1e-3 gives 50-100x headroom,
// so any row NOT flagged is provably decided identically by fp32 and fp64.
#define SCORE_MARGIN 1e-3f
#define ERR_MARGIN   1e-3f

// ---------------------------------------------------------------------------
// Kernel 1: fp32 screening pass. One thread per row. Codebook in LDS
// (norms pre-multiplied by -0.5 so score' = dot - n/2, same ordering as
// 2*dot - n). Tracks top-2 scores per branch; rows whose argmax gap or
// err^2 gap is inside the margin are appended to the ws list for the fp64
// fixup kernel. fp32 results are written for every row (fixup overwrites).
// Output d_out (float32): [final_vals (N*8) | final_idxs (N)].
// ---------------------------------------------------------------------------
__global__ __launch_bounds__(TPB) void e8p_screen(
    const float* __restrict__ X,
    const float* __restrict__ grid_part,
    const float* __restrict__ grid_part_norm,
    const int*   __restrict__ allcombo_idx,
    const int*   __restrict__ idx_map,
    float* __restrict__ out,
    int* __restrict__ ws,      // ws[0]=counter (pre-zeroed), ws[1..]=row ids
    int N, int G, int cap)
{
    extern __shared__ float lds[];
    float* cw = lds;                 // 8*G floats, codewords row-major
    float* cn = lds + 8 * G;         // G floats, -0.5*norm
    int*   im = (int*)(cn + G);      // 256 ints

    const int tid = threadIdx.x;
    for (int k = tid; k < 8 * G; k += TPB) cw[k] = grid_part[k];
    for (int k = tid; k < G; k += TPB)     cn[k] = -0.5f * grid_part_norm[k];
    if (tid < 256) im[tid] = idx_map[tid];
    __syncthreads();

    const int i = blockIdx.x * TPB + tid;
    if (i >= N) return;

    const float4* X4 = (const float4*)(X + (size_t)i * 8);
    float4 a = X4[0], b = X4[1];
    float x[8] = {a.x, a.y, a.z, a.w, b.x, b.y, b.z, b.w};

    // Sign prep (fp32 signs == fp64 signs: correctly-rounded add can't
    // cross zero; exact-zero gives the same >=0 decision in both).
    float yp[8], ym[8], yap[8], yam[8];
    int negp = 0, negm = 0;
#pragma unroll
    for (int j = 0; j < 8; ++j) {
        yp[j] = x[j] + 0.25f;
        ym[j] = x[j] - 0.25f;
        if (yp[j] < 0.0f) negp |= (1 << (7 - j));
        if (ym[j] < 0.0f) negm |= (1 << (7 - j));
        yap[j] = fabsf(yp[j]);
        yam[j] = fabsf(ym[j]);
    }
    int mintp = negp, mintm = negm;
    if (__popc(negp) & 1) { yap[0] = -yap[0]; mintp ^= 128; }
    if (__popc(negm) & 1) { yam[0] = -yam[0]; mintm ^= 128; }

    // fp32 argmax with top-2 tracking (first-max-wins).
    float bestp = -1e30f, bestm = -1e30f;
    float secp = -1e30f, secm = -1e30f;
    int qp = 0, qm = 0;
#pragma unroll 2
    for (int j = 0; j < G; ++j) {
        const float4 g0 = *(const float4*)(cw + (size_t)j * 8);
        const float4 g1 = *(const float4*)(cw + (size_t)j * 8 + 4);
        const float mn = cn[j];   // -0.5*norm
        float dp, dm;
        dp = fmaf(yap[0], g0.x, mn);   dm = fmaf(yam[0], g0.x, mn);
        dp = fmaf(yap[1], g0.y, dp);   dm = fmaf(yam[1], g0.y, dm);
        dp = fmaf(yap[2], g0.z, dp);   dm = fmaf(yam[2], g0.z, dm);
        dp = fmaf(yap[3], g0.w, dp);   dm = fmaf(yam[3], g0.w, dm);
        dp = fmaf(yap[4], g1.x, dp);   dm = fmaf(yam[4], g1.x, dm);
        dp = fmaf(yap[5], g1.y, dp);   dm = fmaf(yam[5], g1.y, dm);
        dp = fmaf(yap[6], g1.z, dp);   dm = fmaf(yam[6], g1.z, dm);
        dp = fmaf(yap[7], g1.w, dp);   dm = fmaf(yam[7], g1.w, dm);
        // top-2 update: second = max(second, min(s, best)); best/q on s>best
        secp = fmaxf(secp, fminf(dp, bestp));
        secm = fmaxf(secm, fminf(dm, bestm));
        if (dp > bestp) { bestp = dp; qp = j; }
        if (dm > bestm) { bestm = dm; qm = j; }
    }

    // Epilogue (fp32): rebuild vals, squared errors.
    const float* gp_ = cw + (size_t)qp * 8;
    const float* gm_ = cw + (size_t)qm * 8;
    float vp[8], vm[8];
    float ep2 = 0.0f, em2 = 0.0f;
#pragma unroll
    for (int j = 0; j < 8; ++j) {
        const float maskp = ((mintp >> (7 - j)) & 1) ? -1.0f : 1.0f;
        const float maskm = ((mintm >> (7 - j)) & 1) ? -1.0f : 1.0f;
        vp[j] = gp_[j] * maskp;
        vm[j] = gm_[j] * maskm;
        const float dpj = yp[j] - vp[j];
        const float dmj = ym[j] - vm[j];
        ep2 = fmaf(dpj, dpj, ep2);
        em2 = fmaf(dmj, dmj, em2);
    }

    const bool close = ((bestp - secp) < SCORE_MARGIN) |
                       ((bestm - secm) < SCORE_MARGIN) |
                       (fabsf(ep2 - em2) < ERR_MARGIN);
    if (close) {
        int slot = atomicAdd(ws, 1);
        if (slot < cap) ws[1 + slot] = i;
    }

    const bool which = ep2 < em2;  // == sqrt compare; safe when not flagged

    const int rowp = im[mintp];
    const int rowm = im[mintm];
    const int pi = allcombo_idx[(size_t)rowp * G + qp];
    const int mi = allcombo_idx[(size_t)rowm * G + qm];
    const float idxval = which ? (float)pi : (float)(mi - 32768);

    float* vout = out + (size_t)i * 8;
#pragma unroll
    for (int j = 0; j < 8; ++j) {
        vout[j] = which ? (vp[j] - 0.25f) : (vm[j] + 0.25f);
    }
    out[(size_t)N * 8 + i] = idxval;
}

// ---------------------------------------------------------------------------
// Kernel 2: fp64 fixup — exact replica of the round-2 arithmetic (verified
// absmax 0.0) for flagged rows only. One WAVE per row: lanes split the
// G-loop 64-way, then (max-score, min-index) shuffle reduce = np.argmax
// first-max-wins. Codebook read from global (L2-resident, coalesced).
// ---------------------------------------------------------------------------
__global__ __launch_bounds__(TPB) void e8p_fix(
    const float* __restrict__ X,
    const float* __restrict__ grid_part,
    const float* __restrict__ grid_part_norm,
    const int*   __restrict__ allcombo_idx,
    const int*   __restrict__ idx_map,
    float* __restrict__ out,
    const int* __restrict__ ws,
    int N, int G, int cap)
{
    const int count = min(ws[0], cap);
    const int lane  = threadIdx.x & 63;
    const int wave  = (blockIdx.x * blockDim.x + threadIdx.x) >> 6;
    const int nwave = (gridDim.x * blockDim.x) >> 6;

    for (int r = wave; r < count; r += nwave) {
        const int i = ws[1 + r];

        const float4* X4 = (const float4*)(X + (size_t)i * 8);
        float4 a = X4[0], b = X4[1];
        float x[8] = {a.x, a.y, a.z, a.w, b.x, b.y, b.z, b.w};

        double yap[8], yam[8];
        int negp = 0, negm = 0;
#pragma unroll
        for (int j = 0; j < 8; ++j) {
            const double xd = (double)x[j];
            const double ypj = xd + 0.25;
            const double ymj = xd - 0.25;
            if (ypj < 0.0) negp |= (1 << (7 - j));
            if (ymj < 0.0) negm |= (1 << (7 - j));
            yap[j] = fabs(ypj);
            yam[j] = fabs(ymj);
        }
        int mintp = negp, mintm = negm;
        if (__popc(negp) & 1) { yap[0] = -yap[0]; mintp ^= 128; }
        if (__popc(negm) & 1) { yam[0] = -yam[0]; mintm ^= 128; }

        double bestp = -1e300, bestm = -1e300;
        int qp = 0x7fffffff, qm = 0x7fffffff;
        for (int j = lane; j < G; j += 64) {
            const float4 g0 = *(const float4*)(grid_part + (size_t)j * 8);
            const float4 g1 = *(const float4*)(grid_part + (size_t)j * 8 + 4);
            const double n = (double)grid_part_norm[j];
            const double t0 = (double)g0.x, t1 = (double)g0.y,
                         t2 = (double)g0.z, t3 = (double)g0.w,
                         t4 = (double)g1.x, t5 = (double)g1.y,
                         t6 = (double)g1.z, t7 = (double)g1.w;
            double dp, dm;
            dp = yap[0] * t0;           dm = yam[0] * t0;
            dp = fma(yap[1], t1, dp);   dm = fma(yam[1], t1, dm);
            dp = fma(yap[2], t2, dp);   dm = fma(yam[2], t2, dm);
            dp = fma(yap[3], t3, dp);   dm = fma(yam[3], t3, dm);
            dp = fma(yap[4], t4, dp);   dm = fma(yam[4], t4, dm);
            dp = fma(yap[5], t5, dp);   dm = fma(yam[5], t5, dm);
            dp = fma(yap[6], t6, dp);   dm = fma(yam[6], t6, dm);
            dp = fma(yap[7], t7, dp);   dm = fma(yam[7], t7, dm);
            const double sp = 2.0 * dp - n;
            const double sm = 2.0 * dm - n;
            if (sp > bestp) { bestp = sp; qp = j; }
            if (sm > bestm) { bestm = sm; qm = j; }
        }
        // (max score, min index) butterfly reduce == np.argmax first-max-wins
#pragma unroll
        for (int off = 32; off > 0; off >>= 1) {
            double ob = __shfl_xor(bestp, off, 64);
            int    oq = __shfl_xor(qp, off, 64);
            if (ob > bestp || (ob == bestp && oq < qp)) { bestp = ob; qp = oq; }
            ob = __shfl_xor(bestm, off, 64);
            oq = __shfl_xor(qm, off, 64);
            if (ob > bestm || (ob == bestm && oq < qm)) { bestm = ob; qm = oq; }
        }

        if (lane == 0) {
            const float* gp_ = grid_part + (size_t)qp * 8;
            const float* gm_ = grid_part + (size_t)qm * 8;
            double vp[8], vm[8];
            double ep2 = 0.0, em2 = 0.0;
#pragma unroll
            for (int j = 0; j < 8; ++j) {
                const double maskp = ((mintp >> (7 - j)) & 1) ? -1.0 : 1.0;
                const double maskm = ((mintm >> (7 - j)) & 1) ? -1.0 : 1.0;
                vp[j] = (double)gp_[j] * maskp;
                vm[j] = (double)gm_[j] * maskm;
                const double xd = (double)x[j];
                const double dpj = (xd + 0.25) - vp[j];
                const double dmj = (xd - 0.25) - vm[j];
                ep2 += dpj * dpj;
                em2 += dmj * dmj;
            }
            const double ep = sqrt(ep2), em = sqrt(em2);
            const bool which = ep < em;

            const int rowp = idx_map[mintp];
            const int rowm = idx_map[mintm];
            const int pi = allcombo_idx[(size_t)rowp * G + qp];
            const int mi = allcombo_idx[(size_t)rowm * G + qm];
            const float idxval = which ? (float)pi : (float)(mi - 32768);

            float* vout = out + (size_t)i * 8;
#pragma unroll
            for (int j = 0; j < 8; ++j) {
                const double v = which ? (vp[j] - 0.25) : (vm[j] + 0.25);
                vout[j] = (float)v;
            }
            out[(size_t)N * 8 + i] = idxval;
        }
    }
}

extern "C" void kernel_launch(void* const* d_in, const int* in_sizes, int n_in,
                              void* d_out, int out_size, void* d_ws, size_t ws_size,
                              hipStream_t stream) {
    const float* X    = (const float*)d_in[0];
    const float* gp   = (const float*)d_in[1];
    const float* gn   = (const float*)d_in[2];
    const int*   aci  = (const int*)d_in[3];
    const int*   imap = (const int*)d_in[4];
    // d_in[5] (int_map) and d_in[6] (grid_idx_map) are folded analytically.

    const int N = in_sizes[0] / 8;
    const int G = in_sizes[1] / 8;
    const size_t shmem = (size_t)(9 * G + 256) * sizeof(float);
    const int blocks = (N + TPB - 1) / TPB;

    int* ws = (int*)d_ws;
    long long capl = (long long)(ws_size / 4) - 1;
    if (capl < 0) capl = 0;
    if (capl > N) capl = N;
    const int cap = (int)capl;

    hipMemsetAsync(ws, 0, sizeof(int), stream);  // zero the flag counter

    hipLaunchKernelGGL(e8p_screen, dim3(blocks), dim3(TPB), shmem, stream,
                       X, gp, gn, aci, imap, (float*)d_out, ws, N, G, cap);
    // 256 blocks x 256 thr = 1024 waves; grid-strides if count > 1024.
    hipLaunchKernelGGL(e8p_fix, dim3(256), dim3(TPB), 0, stream,
                       X, gp, gn, aci, imap, (float*)d_out, ws, N, G, cap);
}